// Round 4
// baseline (346.146 us; speedup 1.0000x reference)
//
#include <hip/hip_runtime.h>
#include <hip/hip_bf16.h>
#include <stdint.h>

#define ENC_DIM 2048
#define ATT_DIM 512
#define BATCH   256
#define NPIX    196
#define CTX_OFF (BATCH*ENC_DIM)       // context, then alpha
#define KC      128                   // K per chunk
#define NITER   32                    // 2 subtiles x 16 chunks
#define MSUB    112                   // rows per M-subtile (7 x 16)
#define ABUF    (MSUB*KC*2)           // 28672 bytes per A buffer

typedef __attribute__((ext_vector_type(8))) short  short8;
typedef __attribute__((ext_vector_type(4))) float  f32x4;

__device__ __forceinline__ uint32_t f2bf(float x) {
    union { float f; uint32_t u; } v; v.f = x;
    return (v.u + 0x7FFFu + ((v.u >> 16) & 1u)) >> 16;
}

// ---------------------------------------------------------------------------
// Kernel 0: pack W_enc (fp32 [2048][512]) -> bf16 Wp[(k/8)*512 + n][8]
// ---------------------------------------------------------------------------
__global__ __launch_bounds__(256) void pack_wenc(const float* __restrict__ W,
                                                 unsigned short* __restrict__ Wp) {
    const int i  = blockIdx.x * 256 + threadIdx.x;   // 0 .. 131071
    const int n  = i & 511;
    const int kg = i >> 9;
    short8 v;
#pragma unroll
    for (int j = 0; j < 8; ++j)
        v[j] = (short)f2bf(W[(size_t)(kg * 8 + j) * 512 + n]);
    *(short8*)(Wp + (size_t)i * 8) = v;
}

// ---------------------------------------------------------------------------
// Kernel 1: att2p[b][a] = hidden[b,:] @ W_dec[:,a] + b_dec[a] + b_enc[a]
// ---------------------------------------------------------------------------
__global__ __launch_bounds__(256) void att2_kernel(const float* __restrict__ hidden,
                                                   const float* __restrict__ Wdec,
                                                   const float* __restrict__ bdec,
                                                   const float* __restrict__ benc,
                                                   float* __restrict__ att2p) {
    __shared__ float h[512];
    const int b   = blockIdx.x;
    const int tid = threadIdx.x;
    h[tid]       = hidden[(size_t)b * 512 + tid];
    h[tid + 256] = hidden[(size_t)b * 512 + tid + 256];
    __syncthreads();
    float acc0 = bdec[tid]       + benc[tid];
    float acc1 = bdec[tid + 256] + benc[tid + 256];
#pragma unroll 4
    for (int k = 0; k < 512; ++k) {
        const float hk = h[k];
        acc0 = fmaf(hk, Wdec[(size_t)k * 512 + tid],       acc0);
        acc1 = fmaf(hk, Wdec[(size_t)k * 512 + tid + 256], acc1);
    }
    att2p[(size_t)b * 512 + tid]       = acc0;
    att2p[(size_t)b * 512 + tid + 256] = acc1;
}

// ---------------------------------------------------------------------------
// Fused kernel: one block per batch, 768 threads.
//   waves 0-7  (tid < 512): consumers — MFMA from LDS-A + L2-B (pure-B vmcnt)
//   waves 8-11 (tid >= 512): producers — stage A fp32->bf16 into LDS (dbuf)
// Then block softmax + context.
// ---------------------------------------------------------------------------
__global__ __launch_bounds__(768, 3) void fused_kernel(const float* __restrict__ enc,
                                                       const unsigned short* __restrict__ Wp,
                                                       const float* __restrict__ att2p,
                                                       const float* __restrict__ Wfull,
                                                       float* __restrict__ out) {
    __shared__ __align__(16) unsigned char ldsA[2][ABUF];   // 56 KB
    __shared__ float lds_att2[ATT_DIM];
    __shared__ float lds_wf[ATT_DIM];
    __shared__ float lds_sc[224];
    __shared__ float salpha[NPIX];
    __shared__ float red[16];

    const int tid = threadIdx.x;
    const int b   = blockIdx.x;
    const bool isProd = (tid >= 512);

    if (tid < 512) {
        lds_att2[tid] = att2p[(size_t)b * ATT_DIM + tid];
        lds_wf[tid]   = Wfull[tid];
    }
    if (tid < 224) lds_sc[tid] = 0.0f;

    // ---------------- consumer constants ----------------
    const int w    = tid >> 6;            // 0..7 for consumers
    const int l    = tid & 63;
    const int kq   = l >> 4;              // 0..3
    const int key2 = ((l & 7) << 1) ^ ((l >> 3) & 1);
    const int afrow = (l & 15) << 8;      // row-part of A frag byte offset
    int boff[4];
#pragma unroll
    for (int nf = 0; nf < 4; ++nf)
        boff[nf] = ((kq * 512) + (w << 6) + (nf << 4) + (l & 15)) * 8;

    // ---------------- producer constants ----------------
    const int  pt    = tid - 512;                       // 0..255
    const bool pact  = isProd && (pt < 224);
    const int  prow  = pt >> 1;                         // 0..111
    const int  phalf = pt & 1;
    const int  pkey  = ((prow & 7) << 1) ^ ((prow >> 3) & 1);
    int woff[8];
#pragma unroll
    for (int j2 = 0; j2 < 8; ++j2)
        woff[j2] = prow * 256 + (((phalf * 8 + j2) ^ pkey) << 4);
    int pix1 = 112 + prow; if (pix1 > NPIX - 1) pix1 = NPIX - 1;
    const float* pbase0 = enc + ((size_t)b * NPIX + prow) * ENC_DIM + phalf * 64;
    const float* pbase1 = enc + ((size_t)b * NPIX + pix1) * ENC_DIM + phalf * 64;

#define PRODUCE(J, DSTBUF)                                                     \
    {                                                                          \
        const float* src = (((J) >> 4) ? pbase1 : pbase0) + ((J) & 15) * KC;   \
        f32x4 r[16];                                                           \
        _Pragma("unroll")                                                      \
        for (int t = 0; t < 16; ++t) r[t] = *(const f32x4*)(src + t * 4);      \
        unsigned char* ldsW = ldsA[(DSTBUF)];                                  \
        _Pragma("unroll")                                                      \
        for (int j2 = 0; j2 < 8; ++j2) {                                       \
            uint4 wv;                                                          \
            wv.x = f2bf(r[2*j2][0])   | (f2bf(r[2*j2][1])   << 16);            \
            wv.y = f2bf(r[2*j2][2])   | (f2bf(r[2*j2][3])   << 16);            \
            wv.z = f2bf(r[2*j2+1][0]) | (f2bf(r[2*j2+1][1]) << 16);            \
            wv.w = f2bf(r[2*j2+1][2]) | (f2bf(r[2*j2+1][3]) << 16);            \
            *(uint4*)(ldsW + woff[j2]) = wv;                                   \
        }                                                                      \
    }

    // ---- prologue: producers stage chunk 0 into buffer 0 ----
    if (pact) PRODUCE(0, 0)
    __syncthreads();

    f32x4 acc[7][4];
#pragma unroll
    for (int i = 0; i < 7; ++i)
#pragma unroll
        for (int j = 0; j < 4; ++j)
            acc[i][j] = (f32x4){0.f, 0.f, 0.f, 0.f};

#define STEP(S, B)                                                             \
    {                                                                          \
        const int so = (((S) * 4 + kq) ^ key2) << 4;                           \
        _Pragma("unroll")                                                      \
        for (int mf = 0; mf < 7; ++mf) {                                       \
            short8 af = *(const short8*)(ldsR + afrow + so + mf * 4096);       \
            _Pragma("unroll")                                                  \
            for (int nf = 0; nf < 4; ++nf)                                     \
                acc[mf][nf] = __builtin_amdgcn_mfma_f32_16x16x32_bf16(         \
                    af, B[nf], acc[mf][nf], 0, 0, 0);                          \
        }                                                                      \
    }

#pragma unroll 1
    for (int i = 0; i < NITER; ++i) {
        const int p = i & 1;
        if (!isProd) {
            const unsigned char*  ldsR = ldsA[p];
            const unsigned short* bC   = Wp + (size_t)(i & 15) * 65536;
            short8 b0[4], b1[4], b2[4], b3[4];
#pragma unroll
            for (int nf = 0; nf < 4; ++nf) b0[nf] = *(const short8*)(bC + boff[nf]);
#pragma unroll
            for (int nf = 0; nf < 4; ++nf) b1[nf] = *(const short8*)(bC + boff[nf] + 16384);
            STEP(0, b0)
#pragma unroll
            for (int nf = 0; nf < 4; ++nf) b2[nf] = *(const short8*)(bC + boff[nf] + 32768);
            STEP(1, b1)
#pragma unroll
            for (int nf = 0; nf < 4; ++nf) b3[nf] = *(const short8*)(bC + boff[nf] + 49152);
            STEP(2, b2)
            STEP(3, b3)

            if (i == 15 || i == 31) {
                const int sub = i >> 4;
                // epilogue: bias + relu + dot(Wf) -> per-row partial scores
#pragma unroll
                for (int mf = 0; mf < 7; ++mf) {
#pragma unroll
                    for (int reg = 0; reg < 4; ++reg) {
                        const int row = sub * MSUB + mf * 16 + ((l >> 4) << 2) + reg;
                        float sv = 0.0f;
#pragma unroll
                        for (int nf = 0; nf < 4; ++nf) {
                            const int col = (w << 6) + (nf << 4) + (l & 15);
                            float v = acc[mf][nf][reg] + lds_att2[col];
                            v = fmaxf(v, 0.0f);
                            sv = fmaf(v, lds_wf[col], sv);
                        }
                        sv += __shfl_xor(sv, 8);
                        sv += __shfl_xor(sv, 4);
                        sv += __shfl_xor(sv, 2);
                        sv += __shfl_xor(sv, 1);
                        if ((l & 15) == 0 && row < NPIX) atomicAdd(&lds_sc[row], sv);
                    }
                }
#pragma unroll
                for (int mf = 0; mf < 7; ++mf)
#pragma unroll
                    for (int nf = 0; nf < 4; ++nf)
                        acc[mf][nf] = (f32x4){0.f, 0.f, 0.f, 0.f};
            }
        } else if (pact) {
            if (i < NITER - 1) PRODUCE(i + 1, p ^ 1)
        }
        __syncthreads();
    }
#undef STEP
#undef PRODUCE

    // ---- softmax over 196 pixels (12 waves) ----
    const float sval = (tid < NPIX) ? lds_sc[tid] : -1e30f;
    float mx = sval;
#pragma unroll
    for (int m = 32; m >= 1; m >>= 1) mx = fmaxf(mx, __shfl_xor(mx, m));
    if (l == 0) red[tid >> 6] = mx;
    __syncthreads();
    if (tid == 0) {
        float m2 = red[0];
#pragma unroll
        for (int i = 1; i < 12; ++i) m2 = fmaxf(m2, red[i]);
        red[12] = m2;
    }
    __syncthreads();
    const float bm = red[12];
    const float ex = (tid < NPIX) ? __expf(sval - bm) : 0.0f;
    float sm = ex;
#pragma unroll
    for (int m = 32; m >= 1; m >>= 1) sm += __shfl_xor(sm, m);
    if (l == 0) red[tid >> 6] = sm;
    __syncthreads();
    if (tid == 0) {
        float s2 = 0.f;
#pragma unroll
        for (int i = 0; i < 12; ++i) s2 += red[i];
        red[13] = s2;
    }
    __syncthreads();
    const float inv = 1.0f / red[13];
    if (tid < NPIX) {
        const float av = ex * inv;
        salpha[tid] = av;
        out[CTX_OFF + (size_t)b * NPIX + tid] = av;
    }
    __syncthreads();

    // ---- phase 3: context[b,:] = sum_n alpha[n] * enc[b,n,:] (waves 0-7) ----
    if (tid < 512) {
        const float* ep = enc + (size_t)b * NPIX * ENC_DIM + tid * 4;
        f32x4 a2 = (f32x4){0.f, 0.f, 0.f, 0.f};
#pragma unroll 4
        for (int n = 0; n < NPIX; ++n)
            a2 += salpha[n] * *(const f32x4*)(ep + (size_t)n * ENC_DIM);
        *(f32x4*)(out + (size_t)b * ENC_DIM + tid * 4) = a2;
    }
}

// ---------------------------------------------------------------------------
extern "C" void kernel_launch(void* const* d_in, const int* in_sizes, int n_in,
                              void* d_out, int out_size, void* d_ws, size_t ws_size,
                              hipStream_t stream) {
    const float* enc    = (const float*)d_in[0];
    const float* hidden = (const float*)d_in[1];
    const float* Wenc   = (const float*)d_in[2];
    const float* benc   = (const float*)d_in[3];
    const float* Wdec   = (const float*)d_in[4];
    const float* bdec   = (const float*)d_in[5];
    const float* Wfull  = (const float*)d_in[6];
    // d_in[7] = b_full: softmax-shift-invariant, unused.
    float* out = (float*)d_out;

    unsigned short* Wp    = (unsigned short*)d_ws;                   // 2 MB
    float*          att2p = (float*)((char*)d_ws + (2u << 20));      // 512 KB

    pack_wenc   <<<512, 256, 0, stream>>>(Wenc, Wp);
    att2_kernel <<<BATCH, 256, 0, stream>>>(hidden, Wdec, bdec, benc, att2p);
    fused_kernel<<<BATCH, 768, 0, stream>>>(enc, Wp, att2p, Wfull, out);
}

// Round 5
// 313.433 us; speedup vs baseline: 1.1044x; 1.1044x over previous
//
#include <hip/hip_runtime.h>
#include <hip/hip_bf16.h>
#include <stdint.h>

#define ENC_DIM 2048
#define ATT_DIM 512
#define BATCH   256
#define NPIX    196
#define MROWS   (BATCH*NPIX)          // 50176 = 784 * 64 exactly
#define CTX_OFF (BATCH*ENC_DIM)       // context, then alpha
#define KC      64                    // K per chunk
#define NCH     (ENC_DIM/KC)          // 32

typedef __attribute__((ext_vector_type(8))) short  short8;
typedef __attribute__((ext_vector_type(4))) float  f32x4;

__device__ __forceinline__ uint32_t f2bf(float x) {
    union { float f; uint32_t u; } v; v.f = x;
    return (v.u + 0x7FFFu + ((v.u >> 16) & 1u)) >> 16;
}

// ---------------------------------------------------------------------------
// Kernel 0: pack W_enc (fp32 [2048][512]) -> bf16 Wp[(k/8)*512 + n][8]
// ---------------------------------------------------------------------------
__global__ __launch_bounds__(256) void pack_wenc(const float* __restrict__ W,
                                                 unsigned short* __restrict__ Wp) {
    const int i  = blockIdx.x * 256 + threadIdx.x;   // 0 .. 131071
    const int n  = i & 511;
    const int kg = i >> 9;
    short8 v;
#pragma unroll
    for (int j = 0; j < 8; ++j)
        v[j] = (short)f2bf(W[(size_t)(kg * 8 + j) * 512 + n]);
    *(short8*)(Wp + (size_t)i * 8) = v;
}

// ---------------------------------------------------------------------------
// Kernel 1: att2p[b][a] = hidden[b,:] @ W_dec[:,a] + b_dec[a] + b_enc[a]
// ---------------------------------------------------------------------------
__global__ __launch_bounds__(256) void att2_kernel(const float* __restrict__ hidden,
                                                   const float* __restrict__ Wdec,
                                                   const float* __restrict__ bdec,
                                                   const float* __restrict__ benc,
                                                   float* __restrict__ att2p) {
    __shared__ float h[512];
    const int b   = blockIdx.x;
    const int tid = threadIdx.x;
    h[tid]       = hidden[(size_t)b * 512 + tid];
    h[tid + 256] = hidden[(size_t)b * 512 + tid + 256];
    __syncthreads();
    float acc0 = bdec[tid]       + benc[tid];
    float acc1 = bdec[tid + 256] + benc[tid + 256];
#pragma unroll 4
    for (int k = 0; k < 512; ++k) {
        const float hk = h[k];
        acc0 = fmaf(hk, Wdec[(size_t)k * 512 + tid],       acc0);
        acc1 = fmaf(hk, Wdec[(size_t)k * 512 + tid + 256], acc1);
    }
    att2p[(size_t)b * 512 + tid]       = acc0;
    att2p[(size_t)b * 512 + tid + 256] = acc1;
}

// ---------------------------------------------------------------------------
// Kernel 2: scores. 784 blocks x 512 thr (8 waves). BM=64, BN=512 (64 cols
// per wave). A: reg-staged fp32->bf16 into double-buffered LDS (2x8KB),
// XOR swizzle slot = kg ^ (row&7) — uniform banks both sides. B: direct
// from L2 (Wp is 2MB, resident). One barrier per KC=64 chunk.
// ---------------------------------------------------------------------------
__global__ __launch_bounds__(512, 3) void score_kernel(const float* __restrict__ enc,
                                                       const unsigned short* __restrict__ Wp,
                                                       const float* __restrict__ att2p,
                                                       const float* __restrict__ Wfull,
                                                       float* __restrict__ scores) {
    __shared__ __align__(16) unsigned char ldsA[2][64 * KC * 2];   // 2 x 8 KB
    __shared__ float lds_att2[2][ATT_DIM];
    __shared__ float lds_wf[ATT_DIM];
    __shared__ float lds_sc[64];

    const int tid = threadIdx.x;
    const int w   = tid >> 6;
    const int l   = tid & 63;
    const int m0  = blockIdx.x * 64;
    const int b0  = m0 / NPIX;
    const int b1  = (m0 + 63) / NPIX;

    lds_att2[0][tid] = att2p[(size_t)b0 * ATT_DIM + tid];
    lds_att2[1][tid] = att2p[(size_t)b1 * ATT_DIM + tid];
    lds_wf[tid] = Wfull[tid];
    if (tid < 64) lds_sc[tid] = 0.0f;

    // ---- A staging geometry: thread -> (row 0..63, k-octet 0..7) ----
    const int arow = tid >> 3;
    const int akg  = tid & 7;
    const int awr  = arow * 128 + ((akg ^ (arow & 7)) << 4);   // byte offset
    const float* aG = enc + (size_t)(m0 + arow) * ENC_DIM + akg * 8;

    // ---- A fragment read geometry ----
    int ard[4], akey[4];
#pragma unroll
    for (int mf = 0; mf < 4; ++mf) {
        const int r = mf * 16 + (l & 15);
        ard[mf]  = r * 128;
        akey[mf] = r & 7;
    }
    const int kq = l >> 4;   // 0..3

    // ---- B global offsets (shorts) ----
    int boff[4];
#pragma unroll
    for (int nf = 0; nf < 4; ++nf)
        boff[nf] = (kq * 512 + (w << 6) + (nf << 4) + (l & 15)) * 8;

    f32x4 acc[4][4];
#pragma unroll
    for (int i = 0; i < 4; ++i)
#pragma unroll
        for (int j = 0; j < 4; ++j)
            acc[i][j] = (f32x4){0.f, 0.f, 0.f, 0.f};

    // ---- prologue: stage chunk 0 -> buffer 0 ----
    {
        f32x4 a0 = *(const f32x4*)aG;
        f32x4 a1 = *(const f32x4*)(aG + 4);
        uint4 u;
        u.x = f2bf(a0[0]) | (f2bf(a0[1]) << 16);
        u.y = f2bf(a0[2]) | (f2bf(a0[3]) << 16);
        u.z = f2bf(a1[0]) | (f2bf(a1[1]) << 16);
        u.w = f2bf(a1[2]) | (f2bf(a1[3]) << 16);
        *(uint4*)(ldsA[0] + awr) = u;
    }
    __syncthreads();

#define STEP(S, BV)                                                            \
    {                                                                          \
        _Pragma("unroll")                                                      \
        for (int mf = 0; mf < 4; ++mf) {                                       \
            short8 af = *(const short8*)(ldsR + ard[mf] +                      \
                                         ((((S) * 4 + kq) ^ akey[mf]) << 4));  \
            _Pragma("unroll")                                                  \
            for (int nf = 0; nf < 4; ++nf)                                     \
                acc[mf][nf] = __builtin_amdgcn_mfma_f32_16x16x32_bf16(         \
                    af, BV[nf], acc[mf][nf], 0, 0, 0);                         \
        }                                                                      \
    }

#pragma unroll 1
    for (int c = 0; c < NCH; ++c) {
        const int p = c & 1;
        const unsigned char* ldsR = ldsA[p];
        const unsigned short* bC  = Wp + (size_t)c * 32768;
        short8 b0v[4], b1v[4];
#pragma unroll
        for (int nf = 0; nf < 4; ++nf) b0v[nf] = *(const short8*)(bC + boff[nf]);
#pragma unroll
        for (int nf = 0; nf < 4; ++nf) b1v[nf] = *(const short8*)(bC + boff[nf] + 16384);
        f32x4 an0, an1;
        if (c < NCH - 1) {
            an0 = *(const f32x4*)(aG + (c + 1) * KC);
            an1 = *(const f32x4*)(aG + (c + 1) * KC + 4);
        }
        STEP(0, b0v)
        if (c < NCH - 1) {
            uint4 u;
            u.x = f2bf(an0[0]) | (f2bf(an0[1]) << 16);
            u.y = f2bf(an0[2]) | (f2bf(an0[3]) << 16);
            u.z = f2bf(an1[0]) | (f2bf(an1[1]) << 16);
            u.w = f2bf(an1[2]) | (f2bf(an1[3]) << 16);
            *(uint4*)(ldsA[p ^ 1] + awr) = u;
        }
        STEP(1, b1v)
        __syncthreads();
    }
#undef STEP

    // ---- epilogue: bias + relu + dot(Wf), reduce to per-row scores ----
#pragma unroll
    for (int mf = 0; mf < 4; ++mf) {
#pragma unroll
        for (int reg = 0; reg < 4; ++reg) {
            const int row = mf * 16 + ((l >> 4) << 2) + reg;
            const int sel = ((m0 + row) >= (b0 + 1) * NPIX) ? 1 : 0;
            float sv = 0.0f;
#pragma unroll
            for (int nf = 0; nf < 4; ++nf) {
                const int col = (w << 6) + (nf << 4) + (l & 15);
                float v = acc[mf][nf][reg] + lds_att2[sel][col];
                v = fmaxf(v, 0.0f);
                sv = fmaf(v, lds_wf[col], sv);
            }
            sv += __shfl_xor(sv, 8);
            sv += __shfl_xor(sv, 4);
            sv += __shfl_xor(sv, 2);
            sv += __shfl_xor(sv, 1);
            if ((l & 15) == 0) atomicAdd(&lds_sc[row], sv);
        }
    }
    __syncthreads();
    if (tid < 64) scores[m0 + tid] = lds_sc[tid];
}

// ---------------------------------------------------------------------------
// Kernel 3: softmax + context. grid = B x 4 e-quarters; 256 thr;
// thread owns float4 of e, covers half the pixels; LDS combine.
// ---------------------------------------------------------------------------
__global__ __launch_bounds__(256) void ctx_kernel(const float* __restrict__ enc,
                                                  const float* __restrict__ scores,
                                                  float* __restrict__ out) {
    __shared__ float salpha[NPIX];
    __shared__ float red[8];
    __shared__ float partial[512];
    const int tid  = threadIdx.x;
    const int lane = tid & 63;
    const int wid  = tid >> 6;
    const int b    = blockIdx.x >> 2;
    const int eq   = blockIdx.x & 3;

    const float sv = (tid < NPIX) ? scores[(size_t)b * NPIX + tid] : -1e30f;
    float mx = sv;
#pragma unroll
    for (int m = 32; m >= 1; m >>= 1) mx = fmaxf(mx, __shfl_xor(mx, m));
    if (lane == 0) red[wid] = mx;
    __syncthreads();
    if (tid == 0) red[4] = fmaxf(fmaxf(red[0], red[1]), fmaxf(red[2], red[3]));
    __syncthreads();
    const float bm = red[4];
    const float ex = (tid < NPIX) ? __expf(sv - bm) : 0.0f;
    float sm = ex;
#pragma unroll
    for (int m = 32; m >= 1; m >>= 1) sm += __shfl_xor(sm, m);
    if (lane == 0) red[wid] = sm;
    __syncthreads();
    if (tid == 0) red[5] = red[0] + red[1] + red[2] + red[3];
    __syncthreads();
    const float inv = 1.0f / red[5];
    if (tid < NPIX) {
        const float av = ex * inv;
        salpha[tid] = av;
        if (eq == 0) out[CTX_OFF + (size_t)b * NPIX + tid] = av;
    }
    __syncthreads();

    const int l128 = tid & 127;
    const int ph   = tid >> 7;
    const float* ep = enc + (size_t)b * NPIX * ENC_DIM + eq * 512 + l128 * 4;
    f32x4 acc = (f32x4){0.f, 0.f, 0.f, 0.f};
#pragma unroll 4
    for (int n = ph; n < NPIX; n += 2) {
        const float al = salpha[n];
        f32x4 v = *(const f32x4*)(ep + (size_t)n * ENC_DIM);
        acc += v * al;
    }
    if (ph == 1) *(f32x4*)(partial + l128 * 4) = acc;
    __syncthreads();
    if (ph == 0) {
        f32x4 o = acc + *(const f32x4*)(partial + l128 * 4);
        *(f32x4*)(out + (size_t)b * ENC_DIM + eq * 512 + l128 * 4) = o;
    }
}

// ---------------------------------------------------------------------------
extern "C" void kernel_launch(void* const* d_in, const int* in_sizes, int n_in,
                              void* d_out, int out_size, void* d_ws, size_t ws_size,
                              hipStream_t stream) {
    const float* enc    = (const float*)d_in[0];
    const float* hidden = (const float*)d_in[1];
    const float* Wenc   = (const float*)d_in[2];
    const float* benc   = (const float*)d_in[3];
    const float* Wdec   = (const float*)d_in[4];
    const float* bdec   = (const float*)d_in[5];
    const float* Wfull  = (const float*)d_in[6];
    // d_in[7] = b_full: softmax-shift-invariant, unused.
    float* out = (float*)d_out;

    unsigned short* Wp    = (unsigned short*)d_ws;                              // 2 MB
    float*          att2p = (float*)((char*)d_ws + (2u << 20));                 // 512 KB
    float*          scores= (float*)((char*)d_ws + (2u << 20) + (512u << 10));  // 200 KB

    pack_wenc   <<<512, 256, 0, stream>>>(Wenc, Wp);
    att2_kernel <<<BATCH, 256, 0, stream>>>(hidden, Wdec, bdec, benc, att2p);
    score_kernel<<<MROWS / 64, 512, 0, stream>>>(enc, Wp, att2p, Wfull, scores);
    ctx_kernel  <<<BATCH * 4, 256, 0, stream>>>(enc, scores, out);
}

// Round 6
// 290.112 us; speedup vs baseline: 1.1931x; 1.0804x over previous
//
#include <hip/hip_runtime.h>
#include <hip/hip_bf16.h>
#include <stdint.h>

#define ENC_DIM 2048
#define ATT_DIM 512
#define BATCH   256
#define NPIX    196
#define MROWS   (BATCH*NPIX)          // 50176 = 784 * 64 exactly
#define CTX_OFF (BATCH*ENC_DIM)       // context, then alpha
#define KC      64                    // K per chunk
#define NCH     (ENC_DIM/KC)          // 32

typedef __attribute__((ext_vector_type(8))) short  short8;
typedef __attribute__((ext_vector_type(4))) float  f32x4;

__device__ __forceinline__ uint32_t f2bf(float x) {
    union { float f; uint32_t u; } v; v.f = x;
    return (v.u + 0x7FFFu + ((v.u >> 16) & 1u)) >> 16;
}

__device__ __forceinline__ uint4 pack8(f32x4 a0, f32x4 a1) {
    uint4 u;
    u.x = f2bf(a0[0]) | (f2bf(a0[1]) << 16);
    u.y = f2bf(a0[2]) | (f2bf(a0[3]) << 16);
    u.z = f2bf(a1[0]) | (f2bf(a1[1]) << 16);
    u.w = f2bf(a1[2]) | (f2bf(a1[3]) << 16);
    return u;
}

// ---------------------------------------------------------------------------
// Kernel 0: pack W_enc (fp32 [2048][512]) -> bf16 Wp[(k/8)*512 + n][8]
// ---------------------------------------------------------------------------
__global__ __launch_bounds__(256) void pack_wenc(const float* __restrict__ W,
                                                 unsigned short* __restrict__ Wp) {
    const int i  = blockIdx.x * 256 + threadIdx.x;   // 0 .. 131071
    const int n  = i & 511;
    const int kg = i >> 9;
    short8 v;
#pragma unroll
    for (int j = 0; j < 8; ++j)
        v[j] = (short)f2bf(W[(size_t)(kg * 8 + j) * 512 + n]);
    *(short8*)(Wp + (size_t)i * 8) = v;
}

// ---------------------------------------------------------------------------
// Kernel 1: att2p[b][a] = hidden[b,:] @ W_dec[:,a] + b_dec[a] + b_enc[a]
// ---------------------------------------------------------------------------
__global__ __launch_bounds__(256) void att2_kernel(const float* __restrict__ hidden,
                                                   const float* __restrict__ Wdec,
                                                   const float* __restrict__ bdec,
                                                   const float* __restrict__ benc,
                                                   float* __restrict__ att2p) {
    __shared__ float h[512];
    const int b   = blockIdx.x;
    const int tid = threadIdx.x;
    h[tid]       = hidden[(size_t)b * 512 + tid];
    h[tid + 256] = hidden[(size_t)b * 512 + tid + 256];
    __syncthreads();
    float acc0 = bdec[tid]       + benc[tid];
    float acc1 = bdec[tid + 256] + benc[tid + 256];
#pragma unroll 4
    for (int k = 0; k < 512; ++k) {
        const float hk = h[k];
        acc0 = fmaf(hk, Wdec[(size_t)k * 512 + tid],       acc0);
        acc1 = fmaf(hk, Wdec[(size_t)k * 512 + tid + 256], acc1);
    }
    att2p[(size_t)b * 512 + tid]       = acc0;
    att2p[(size_t)b * 512 + tid + 256] = acc1;
}

// ---------------------------------------------------------------------------
// Kernel 2: scores. 784 blocks x 512 thr (8 waves). BM=64, BN=512.
// A: fp32->bf16 reg-staged, TWO-chunk-deep register prefetch, ds_write
//    placed AFTER the MFMAs (no vmcnt(0)/lgkm chaining in the loop).
// B: direct from L2 (Wp 2MB resident). One barrier per KC=64 chunk.
// ---------------------------------------------------------------------------
__global__ __launch_bounds__(512, 2) void score_kernel(const float* __restrict__ enc,
                                                       const unsigned short* __restrict__ Wp,
                                                       const float* __restrict__ att2p,
                                                       const float* __restrict__ Wfull,
                                                       float* __restrict__ scores) {
    __shared__ __align__(16) unsigned char ldsA[2][64 * KC * 2];   // 2 x 8 KB
    __shared__ float lds_att2[2][ATT_DIM];
    __shared__ float lds_wf[ATT_DIM];
    __shared__ float lds_sc[64];

    const int tid = threadIdx.x;
    const int w   = tid >> 6;
    const int l   = tid & 63;
    const int m0  = blockIdx.x * 64;
    const int b0  = m0 / NPIX;
    const int b1  = (m0 + 63) / NPIX;

    lds_att2[0][tid] = att2p[(size_t)b0 * ATT_DIM + tid];
    lds_att2[1][tid] = att2p[(size_t)b1 * ATT_DIM + tid];
    lds_wf[tid] = Wfull[tid];
    if (tid < 64) lds_sc[tid] = 0.0f;

    // ---- A staging geometry: thread -> (row 0..63, k-octet 0..7) ----
    const int arow = tid >> 3;
    const int akg  = tid & 7;
    const int awr  = arow * 128 + ((akg ^ (arow & 7)) << 4);   // byte offset
    const float* aG = enc + (size_t)(m0 + arow) * ENC_DIM + akg * 8;

    // ---- A fragment read geometry ----
    int ard[4], akey[4];
#pragma unroll
    for (int mf = 0; mf < 4; ++mf) {
        const int r = mf * 16 + (l & 15);
        ard[mf]  = r * 128;
        akey[mf] = r & 7;
    }
    const int kq = l >> 4;   // 0..3

    // ---- B global offsets (shorts) ----
    int boff[4];
#pragma unroll
    for (int nf = 0; nf < 4; ++nf)
        boff[nf] = (kq * 512 + (w << 6) + (nf << 4) + (l & 15)) * 8;

    f32x4 acc[4][4];
#pragma unroll
    for (int i = 0; i < 4; ++i)
#pragma unroll
        for (int j = 0; j < 4; ++j)
            acc[i][j] = (f32x4){0.f, 0.f, 0.f, 0.f};

    // ---- prologue: stage chunk 0 -> buffer 0; preload chunk 1 to regs ----
    {
        f32x4 a0 = *(const f32x4*)aG;
        f32x4 a1 = *(const f32x4*)(aG + 4);
        *(uint4*)(ldsA[0] + awr) = pack8(a0, a1);
    }
    f32x4 rc0 = *(const f32x4*)(aG + KC);
    f32x4 rc1 = *(const f32x4*)(aG + KC + 4);
    __syncthreads();

#define STEP(S, BV)                                                            \
    {                                                                          \
        _Pragma("unroll")                                                      \
        for (int mf = 0; mf < 4; ++mf) {                                       \
            short8 af = *(const short8*)(ldsR + ard[mf] +                      \
                                         ((((S) * 4 + kq) ^ akey[mf]) << 4));  \
            _Pragma("unroll")                                                  \
            for (int nf = 0; nf < 4; ++nf)                                     \
                acc[mf][nf] = __builtin_amdgcn_mfma_f32_16x16x32_bf16(         \
                    af, BV[nf], acc[mf][nf], 0, 0, 0);                         \
        }                                                                      \
    }

#pragma unroll 1
    for (int c = 0; c < NCH; ++c) {
        const int p = c & 1;
        const unsigned char* ldsR = ldsA[p];
        const unsigned short* bC  = Wp + (size_t)c * 32768;
        // B loads for this chunk (L2-resident)
        short8 b0v[4], b1v[4];
#pragma unroll
        for (int nf = 0; nf < 4; ++nf) b0v[nf] = *(const short8*)(bC + boff[nf]);
#pragma unroll
        for (int nf = 0; nf < 4; ++nf) b1v[nf] = *(const short8*)(bC + boff[nf] + 16384);
        // issue A loads for chunk c+2 (clamped; redundant tail loads are L1-hot)
        const int cc = (c + 2 < NCH) ? (c + 2) : (NCH - 1);
        f32x4 rn0 = *(const f32x4*)(aG + cc * KC);
        f32x4 rn1 = *(const f32x4*)(aG + cc * KC + 4);
        // compute current chunk
        STEP(0, b0v)
        STEP(1, b1v)
        // write chunk c+1 (loaded one full chunk ago -> latency covered)
        if (c + 1 < NCH)
            *(uint4*)(ldsA[p ^ 1] + awr) = pack8(rc0, rc1);
        __syncthreads();
        rc0 = rn0; rc1 = rn1;
    }
#undef STEP

    // ---- epilogue: bias + relu + dot(Wf), reduce to per-row scores ----
#pragma unroll
    for (int mf = 0; mf < 4; ++mf) {
#pragma unroll
        for (int reg = 0; reg < 4; ++reg) {
            const int row = mf * 16 + ((l >> 4) << 2) + reg;
            const int sel = ((m0 + row) >= (b0 + 1) * NPIX) ? 1 : 0;
            float sv = 0.0f;
#pragma unroll
            for (int nf = 0; nf < 4; ++nf) {
                const int col = (w << 6) + (nf << 4) + (l & 15);
                float v = acc[mf][nf][reg] + lds_att2[sel][col];
                v = fmaxf(v, 0.0f);
                sv = fmaf(v, lds_wf[col], sv);
            }
            sv += __shfl_xor(sv, 8);
            sv += __shfl_xor(sv, 4);
            sv += __shfl_xor(sv, 2);
            sv += __shfl_xor(sv, 1);
            if ((l & 15) == 0) atomicAdd(&lds_sc[row], sv);
        }
    }
    __syncthreads();
    if (tid < 64) scores[m0 + tid] = lds_sc[tid];
}

// ---------------------------------------------------------------------------
// Kernel 3: softmax + context. grid = B x 4 e-quarters; 256 thr;
// thread owns float4 of e, covers half the pixels; LDS combine.
// ---------------------------------------------------------------------------
__global__ __launch_bounds__(256) void ctx_kernel(const float* __restrict__ enc,
                                                  const float* __restrict__ scores,
                                                  float* __restrict__ out) {
    __shared__ float salpha[NPIX];
    __shared__ float red[8];
    __shared__ float partial[512];
    const int tid  = threadIdx.x;
    const int lane = tid & 63;
    const int wid  = tid >> 6;
    const int b    = blockIdx.x >> 2;
    const int eq   = blockIdx.x & 3;

    const float sv = (tid < NPIX) ? scores[(size_t)b * NPIX + tid] : -1e30f;
    float mx = sv;
#pragma unroll
    for (int m = 32; m >= 1; m >>= 1) mx = fmaxf(mx, __shfl_xor(mx, m));
    if (lane == 0) red[wid] = mx;
    __syncthreads();
    if (tid == 0) red[4] = fmaxf(fmaxf(red[0], red[1]), fmaxf(red[2], red[3]));
    __syncthreads();
    const float bm = red[4];
    const float ex = (tid < NPIX) ? __expf(sv - bm) : 0.0f;
    float sm = ex;
#pragma unroll
    for (int m = 32; m >= 1; m >>= 1) sm += __shfl_xor(sm, m);
    if (lane == 0) red[wid] = sm;
    __syncthreads();
    if (tid == 0) red[5] = red[0] + red[1] + red[2] + red[3];
    __syncthreads();
    const float inv = 1.0f / red[5];
    if (tid < NPIX) {
        const float av = ex * inv;
        salpha[tid] = av;
        if (eq == 0) out[CTX_OFF + (size_t)b * NPIX + tid] = av;
    }
    __syncthreads();

    const int l128 = tid & 127;
    const int ph   = tid >> 7;
    const float* ep = enc + (size_t)b * NPIX * ENC_DIM + eq * 512 + l128 * 4;
    f32x4 acc = (f32x4){0.f, 0.f, 0.f, 0.f};
#pragma unroll 4
    for (int n = ph; n < NPIX; n += 2) {
        const float al = salpha[n];
        f32x4 v = *(const f32x4*)(ep + (size_t)n * ENC_DIM);
        acc += v * al;
    }
    if (ph == 1) *(f32x4*)(partial + l128 * 4) = acc;
    __syncthreads();
    if (ph == 0) {
        f32x4 o = acc + *(const f32x4*)(partial + l128 * 4);
        *(f32x4*)(out + (size_t)b * ENC_DIM + eq * 512 + l128 * 4) = o;
    }
}

// ---------------------------------------------------------------------------
extern "C" void kernel_launch(void* const* d_in, const int* in_sizes, int n_in,
                              void* d_out, int out_size, void* d_ws, size_t ws_size,
                              hipStream_t stream) {
    const float* enc    = (const float*)d_in[0];
    const float* hidden = (const float*)d_in[1];
    const float* Wenc   = (const float*)d_in[2];
    const float* benc   = (const float*)d_in[3];
    const float* Wdec   = (const float*)d_in[4];
    const float* bdec   = (const float*)d_in[5];
    const float* Wfull  = (const float*)d_in[6];
    // d_in[7] = b_full: softmax-shift-invariant, unused.
    float* out = (float*)d_out;

    unsigned short* Wp    = (unsigned short*)d_ws;                              // 2 MB
    float*          att2p = (float*)((char*)d_ws + (2u << 20));                 // 512 KB
    float*          scores= (float*)((char*)d_ws + (2u << 20) + (512u << 10));  // 200 KB

    pack_wenc   <<<512, 256, 0, stream>>>(Wenc, Wp);
    att2_kernel <<<BATCH, 256, 0, stream>>>(hidden, Wdec, bdec, benc, att2p);
    score_kernel<<<MROWS / 64, 512, 0, stream>>>(enc, Wp, att2p, Wfull, scores);
    ctx_kernel  <<<BATCH * 4, 256, 0, stream>>>(enc, scores, out);
}